// Round 6
// baseline (191.425 us; speedup 1.0000x reference)
//
#include <hip/hip_runtime.h>
#include <hip/hip_cooperative_groups.h>

namespace cg = cooperative_groups;

#define IN_CH   32
#define OUT_CH  64
#define NFILT   16
#define NINACT  (OUT_CH - NFILT)
#define BATCH   32
#define HW      50176     // 224*224
#define HW4     12544     // HW/4 (float4 elements per plane)
#define CHUNKS  49        // HW4 / 256
#define NPLANE  (BATCH * IN_CH)     // 1024
#define NUNITS  (BATCH * CHUNKS)    // 1568 (256-thread conv units)
#define FGRID   256
#define FBLOCK  512
#define NHALF   (FGRID * 2)         // 512 half-blocks

typedef float vfloat4 __attribute__((ext_vector_type(4)));

// ===========================================================================
// Fused cooperative kernel. grid=256 blocks x 512 threads (1 block/CU is
// always launchable -> cooperative capacity is safe; 2 waves/SIMD).
// Work is done by 512 "half-blocks" of 256 threads.
//  Phase 1: pool — half-block h owns planes h and h+512. Full-plane read +
//           wave/LDS reduce -> pooled[p]. Deterministic partition/order.
//  ---- grid.sync() ----
//  Phase 2: router for ALL 32 samples, block-wide, redundant per block.
//           rank-based top-16 (jax tie-break), rank = compaction index.
//  Phase 3: conv — half-block h processes units h, h+512, ... Right after
//           the sync, all of x (205 MB) is L3-resident: the first sweep's
//           reads hit Infinity Cache before the nt-write stream evicts it.
// ===========================================================================
__global__ __launch_bounds__(FBLOCK, 2) void fused_kernel(
        const float* __restrict__ x,
        const float* __restrict__ weight,
        const float* __restrict__ bias,
        const float* __restrict__ rw,
        const float* __restrict__ rb,
        float* __restrict__ pooled,
        float* __restrict__ out) {

    const int tid  = threadIdx.x;        // 0..511
    const int half = tid >> 8;           // 0 or 1
    const int ht   = tid & 255;          // thread within half-block
    const int hid  = blockIdx.x * 2 + half;  // 0..511

    // ---------------- Phase 1: pool ----------------
    __shared__ float red[2][4];
    const float4* x4 = reinterpret_cast<const float4*>(x);
    #pragma unroll
    for (int rep = 0; rep < 2; ++rep) {
        const int p = hid + rep * NHALF;     // 0..1023
        const float4* xp = x4 + (size_t)p * HW4;
        float s = 0.f;
        for (int i = ht; i < HW4; i += 256) {
            float4 v = xp[i];
            s += (v.x + v.y) + (v.z + v.w);
        }
        for (int off = 32; off > 0; off >>= 1)
            s += __shfl_down(s, off, 64);
        if ((ht & 63) == 0) red[half][ht >> 6] = s;
        __syncthreads();
        if (ht == 0)
            pooled[p] = ((red[half][0] + red[half][1]) +
                         (red[half][2] + red[half][3])) * (1.0f / (float)HW);
        __syncthreads();
    }

    cg::this_grid().sync();

    // ---------------- Phase 2: router (all samples, block-wide) ----------------
    __shared__ float w_s[OUT_CH][IN_CH];           // 8 KB
    __shared__ float b_s[OUT_CH];
    __shared__ float lg[BATCH][OUT_CH];            // 8 KB
    __shared__ unsigned char act[BATCH][OUT_CH];   // 2 KB
    __shared__ short alist[BATCH][NFILT];          // 1 KB
    __shared__ short ilist[BATCH][NINACT];         // 3 KB

    for (int i = tid; i < OUT_CH * IN_CH; i += FBLOCK)
        (&w_s[0][0])[i] = weight[i];
    if (tid < OUT_CH) b_s[tid] = bias[tid];

    for (int p = tid; p < BATCH * OUT_CH; p += FBLOCK) {
        const int b = p >> 6, o = p & 63;
        float acc = rb[o];
        #pragma unroll
        for (int c = 0; c < IN_CH; ++c)
            acc += pooled[b * IN_CH + c] * rw[o * IN_CH + c];
        lg[b][o] = acc;
    }
    __syncthreads();

    for (int p = tid; p < BATCH * OUT_CH; p += FBLOCK) {
        const int b = p >> 6, o = p & 63;
        const float v = lg[b][o];
        int rank = 0;
        #pragma unroll
        for (int j = 0; j < OUT_CH; ++j) {
            const float lj = lg[b][j];
            rank += (lj > v) || (lj == v && j < o);
        }
        const bool a = (rank < NFILT);
        act[b][o] = a;
        if (a) alist[b][rank] = (short)o;
    }
    __syncthreads();

    for (int p = tid; p < BATCH * OUT_CH; p += FBLOCK) {
        const int b = p >> 6, o = p & 63;
        if (!act[b][o]) {
            int irank = 0;
            for (int j = 0; j < o; ++j) irank += !act[b][j];
            ilist[b][irank] = (short)o;
        }
    }
    __syncthreads();

    // ---------------- Phase 3: conv (per half-block; no sync inside) ----------------
    vfloat4* o4 = reinterpret_cast<vfloat4*>(out);

    for (int u = hid; u < NUNITS; u += NHALF) {
        const int b     = u / CHUNKS;
        const int chunk = u - b * CHUNKS;
        const int pos   = chunk * 256 + ht;

        float4 xv[IN_CH];
        #pragma unroll
        for (int c = 0; c < IN_CH; ++c)
            xv[c] = x4[(size_t)(b * IN_CH + c) * HW4 + pos];

        const vfloat4 z = {0.f, 0.f, 0.f, 0.f};
        #pragma unroll
        for (int k = 0; k < NINACT; ++k) {
            const int o = ilist[b][k];
            __builtin_nontemporal_store(z, &o4[(size_t)(b * OUT_CH + o) * HW4 + pos]);
        }

        #pragma unroll
        for (int k = 0; k < NFILT; ++k) {
            const int o = alist[b][k];
            const float bv = b_s[o];
            vfloat4 r = {bv, bv, bv, bv};
            #pragma unroll
            for (int c = 0; c < IN_CH; ++c) {
                const float w = w_s[o][c];
                r.x += w * xv[c].x;
                r.y += w * xv[c].y;
                r.z += w * xv[c].z;
                r.w += w * xv[c].w;
            }
            __builtin_nontemporal_store(r, &o4[(size_t)(b * OUT_CH + o) * HW4 + pos]);
        }
    }
}

// ===========================================================================
// Fallback path (proven R5 kernels) — used if cooperative launch is refused.
// ===========================================================================
__global__ __launch_bounds__(256) void pool_kernel(const float* __restrict__ x,
                                                   float* __restrict__ pooled) {
    const int bc = blockIdx.x;
    const float4* xp = reinterpret_cast<const float4*>(x) + (size_t)bc * HW4;
    float s = 0.f;
    for (int i = threadIdx.x; i < HW4; i += 256) {
        float4 v = xp[i];
        s += (v.x + v.y) + (v.z + v.w);
    }
    for (int off = 32; off > 0; off >>= 1)
        s += __shfl_down(s, off, 64);
    __shared__ float red[4];
    if ((threadIdx.x & 63) == 0) red[threadIdx.x >> 6] = s;
    __syncthreads();
    if (threadIdx.x == 0)
        pooled[bc] = ((red[0] + red[1]) + (red[2] + red[3])) * (1.0f / (float)HW);
}

__global__ __launch_bounds__(256) void conv_kernel(const float* __restrict__ x,
                                                   const float* __restrict__ weight,
                                                   const float* __restrict__ bias,
                                                   const float* __restrict__ rw,
                                                   const float* __restrict__ rb,
                                                   const float* __restrict__ pooled,
                                                   float* __restrict__ out) {
    __shared__ float w_s[OUT_CH][IN_CH];
    __shared__ float b_s[OUT_CH];
    __shared__ float lg[OUT_CH];
    __shared__ unsigned char act[OUT_CH];
    __shared__ short alist[NFILT];
    __shared__ short ilist[NINACT];

    const int b     = blockIdx.x / CHUNKS;
    const int chunk = blockIdx.x % CHUNKS;

    for (int i = threadIdx.x; i < OUT_CH * IN_CH; i += 256)
        (&w_s[0][0])[i] = weight[i];

    if (threadIdx.x < OUT_CH) {
        const int o = threadIdx.x;
        b_s[o] = bias[o];
        float acc = rb[o];
        #pragma unroll
        for (int c = 0; c < IN_CH; ++c)
            acc += pooled[b * IN_CH + c] * rw[o * IN_CH + c];
        lg[o] = acc;
    }
    __syncthreads();

    if (threadIdx.x < OUT_CH) {
        const int o = threadIdx.x;
        const float v = lg[o];
        int rank = 0;
        #pragma unroll
        for (int j = 0; j < OUT_CH; ++j) {
            const float lj = lg[j];
            rank += (lj > v) || (lj == v && j < o);
        }
        const bool a = (rank < NFILT);
        act[o] = a;
        if (a) alist[rank] = (short)o;
    }
    __syncthreads();

    if (threadIdx.x < OUT_CH) {
        const int o = threadIdx.x;
        if (!act[o]) {
            int irank = 0;
            for (int j = 0; j < o; ++j) irank += !act[j];
            ilist[irank] = (short)o;
        }
    }
    __syncthreads();

    const int pos = chunk * 256 + threadIdx.x;
    const float4* x4 = reinterpret_cast<const float4*>(x);
    vfloat4*      o4 = reinterpret_cast<vfloat4*>(out);

    float4 xv[IN_CH];
    #pragma unroll
    for (int c = 0; c < IN_CH; ++c)
        xv[c] = x4[(size_t)(b * IN_CH + c) * HW4 + pos];

    const vfloat4 z = {0.f, 0.f, 0.f, 0.f};
    #pragma unroll
    for (int k = 0; k < NINACT; ++k) {
        const int o = ilist[k];
        __builtin_nontemporal_store(z, &o4[(size_t)(b * OUT_CH + o) * HW4 + pos]);
    }
    #pragma unroll
    for (int k = 0; k < NFILT; ++k) {
        const int o = alist[k];
        const float bv = b_s[o];
        vfloat4 r = {bv, bv, bv, bv};
        #pragma unroll
        for (int c = 0; c < IN_CH; ++c) {
            const float w = w_s[o][c];
            r.x += w * xv[c].x;
            r.y += w * xv[c].y;
            r.z += w * xv[c].z;
            r.w += w * xv[c].w;
        }
        __builtin_nontemporal_store(r, &o4[(size_t)(b * OUT_CH + o) * HW4 + pos]);
    }
}

// ===========================================================================
extern "C" void kernel_launch(void* const* d_in, const int* in_sizes, int n_in,
                              void* d_out, int out_size, void* d_ws, size_t ws_size,
                              hipStream_t stream) {
    const float* x    = (const float*)d_in[0];
    const float* w    = (const float*)d_in[1];
    const float* bias = (const float*)d_in[2];
    const float* rw   = (const float*)d_in[3];
    const float* rb   = (const float*)d_in[4];
    float* out    = (float*)d_out;
    float* pooled = (float*)d_ws;  // NPLANE floats

    void* args[] = {(void*)&x, (void*)&w, (void*)&bias, (void*)&rw,
                    (void*)&rb, (void*)&pooled, (void*)&out};
    hipError_t err = hipLaunchCooperativeKernel((const void*)fused_kernel,
                                                dim3(FGRID), dim3(FBLOCK),
                                                args, 0, stream);
    if (err != hipSuccess) {
        // cooperative launch refused -> proven two-kernel path
        pool_kernel<<<NPLANE, 256, 0, stream>>>(x, pooled);
        conv_kernel<<<NUNITS, 256, 0, stream>>>(x, w, bias, rw, rb, pooled, out);
    }
}